// Round 1
// baseline (255.982 us; speedup 1.0000x reference)
//
#include <hip/hip_runtime.h>
#include <stdint.h>

#define D_DIM 4096
#define N_ROWS 8192

typedef __attribute__((ext_vector_type(8))) short bfrag8;
typedef __attribute__((ext_vector_type(4))) float facc4;

__device__ __forceinline__ uint32_t pack_bf16x2(float lo, float hi) {
    union { float f; uint32_t u; } a, b;
    a.f = lo; b.f = hi;
    return (b.u & 0xFFFF0000u) | (a.u >> 16);   // truncate-to-bf16; only flips near-zero signs (harmless)
}

// ---------------------------------------------------------------------------
// Kernel 0: convert A (fp32 [128][4096]) to bf16, laid out as 64 K-chunks of
// 1024 16B slots, XOR-swizzled so the GEMM can stage it with global_load_lds
// (contiguous, wave-uniform-base) AND read B-fragments via ds_read_b128 with
// only free 2-way bank conflicts.
// slot s of chunk c: n = s>>3, g = (s&7) ^ (n&7), holds A[n][c*64 + g*8 .. +8)
// ---------------------------------------------------------------------------
__global__ void __launch_bounds__(256)
prep_A(const float* __restrict__ A, uint32_t* __restrict__ A_sw) {
    const int S = blockIdx.x * 256 + threadIdx.x;  // 0..65535
    const int c = S >> 10;
    const int s = S & 1023;
    const int n = s >> 3;
    const int g = (s & 7) ^ (n & 7);
    const float* src = A + (size_t)n * D_DIM + c * 64 + g * 8;
    float4 f0 = *(const float4*)(src);
    float4 f1 = *(const float4*)(src + 4);
    uint4 o;
    o.x = pack_bf16x2(f0.x, f0.y);
    o.y = pack_bf16x2(f0.z, f0.w);
    o.z = pack_bf16x2(f1.x, f1.y);
    o.w = pack_bf16x2(f1.z, f1.w);
    *(uint4*)(A_sw + (size_t)S * 4) = o;
}

// ---------------------------------------------------------------------------
// Kernel 1: bf16 MFMA GEMM (32-row M-tile, full N=128, Kc=64) + sign-bit pack
// + 128->64 bit key fold. 256 blocks x 256 threads (4 waves: wm x wn = 2x2,
// each wave 16 rows x 64 cols).
// ---------------------------------------------------------------------------
__global__ void __launch_bounds__(256)
gemm_pack(const float* __restrict__ L, const uint32_t* __restrict__ A_sw,
          unsigned long long* __restrict__ folded) {
    __shared__ ushort Ls[32 * 72];                 // 32 rows x 64 bf16, +8 pad (144B stride: 2-way=free)
    __shared__ uint4 As[1024];                     // 16 KB swizzled bf16 A-chunk
    __shared__ unsigned long long halves[2][32];   // key halves for cross-wave fold

    const int tid  = threadIdx.x;
    const int wave = tid >> 6;
    const int lane = tid & 63;
    const int row0 = blockIdx.x * 32;
    const int c  = lane & 15;
    const int q  = lane >> 4;
    const int wm = wave >> 1;
    const int wn = wave & 1;

    // L staging assignment: thread -> (row, float4-pair)
    const int lrow = tid >> 3;                     // 0..31
    const int lf4  = tid & 7;                      // 0..7
    const float* lsrc = L + (size_t)(row0 + lrow) * D_DIM + lf4 * 4;
    ushort* ldst = &Ls[lrow * 72 + lf4 * 4];

    facc4 acc[4];
#pragma unroll
    for (int i = 0; i < 4; i++) acc[i] = (facc4){0.f, 0.f, 0.f, 0.f};

    for (int kc = 0; kc < D_DIM; kc += 64) {
        // --- A staging: async global->LDS, 16B/lane, swizzled image is contiguous
        const uint32_t* gA = A_sw + (size_t)(kc >> 6) * 4096;
#pragma unroll
        for (int i = 0; i < 4; i++) {
            const int slot0 = wave * 256 + i * 64;
            __builtin_amdgcn_global_load_lds(
                (const __attribute__((address_space(1))) uint32_t*)(gA + (slot0 + lane) * 4),
                (__attribute__((address_space(3))) uint32_t*)(&As[slot0]),
                16, 0, 0);
        }
        // --- L staging: fp32 global -> bf16 LDS (manual, padded stride)
        float4 f0 = *(const float4*)(lsrc + kc);
        float4 f1 = *(const float4*)(lsrc + kc + 32);
        *(uint2*)ldst        = make_uint2(pack_bf16x2(f0.x, f0.y), pack_bf16x2(f0.z, f0.w));
        *(uint2*)(ldst + 32) = make_uint2(pack_bf16x2(f1.x, f1.y), pack_bf16x2(f1.z, f1.w));
        __syncthreads();

#pragma unroll
        for (int ks = 0; ks < 2; ks++) {
            // A-operand: L[m = 16*wm + c][k = ks*32 + q*8 + j]
            bfrag8 a = *(const bfrag8*)&Ls[(16 * wm + c) * 72 + ks * 32 + q * 8];
#pragma unroll
            for (int ct = 0; ct < 4; ct++) {
                const int n  = 64 * wn + 16 * ct + c;   // B-operand: A[n][same k] (B^T form)
                const int gl = ks * 4 + q;
                bfrag8 b = *(const bfrag8*)&As[n * 8 + (gl ^ (n & 7))];
                acc[ct] = __builtin_amdgcn_mfma_f32_16x16x32_bf16(a, b, acc[ct], 0, 0, 0);
            }
        }
        __syncthreads();
    }

    // --- Epilogue: sign bits -> 64-bit half-keys via ballot.
    // C/D layout: col = lane&15 (=n offset), row = q*4 + reg  [m89/m91 verified]
    unsigned long long masks[4][4];
#pragma unroll
    for (int ct = 0; ct < 4; ct++)
#pragma unroll
        for (int r = 0; r < 4; r++)
            masks[ct][r] = __ballot(acc[ct][r] > 0.0f);

    if (lane < 16) {
        // local row m_l = lane = 4*qq + r; bit position within half = 16*ct + col
        const int qq = lane >> 2, r = lane & 3;
        unsigned long long half = 0;
#pragma unroll
        for (int ct = 0; ct < 4; ct++) {
            unsigned long long bits = (masks[ct][r] >> (16 * qq)) & 0xFFFFull;
            half |= bits << (16 * ct);
        }
        halves[wn][16 * wm + lane] = half;   // wn=0: key bits 0..63, wn=1: bits 64..127
    }
    __syncthreads();
    if (tid < 32)
        folded[row0 + tid] = halves[0][tid] ^ halves[1][tid];  // 128->64 bit fold
}

// ---------------------------------------------------------------------------
// Kernel 2: ordered duplicate count. One wave per row i; lanes stride j<=i.
// folded keys (64 KB) are L1/L2 resident; loads are coalesced.
// ---------------------------------------------------------------------------
__global__ void __launch_bounds__(256)
count_rows(const unsigned long long* __restrict__ folded, float* __restrict__ out) {
    const int row  = (blockIdx.x << 2) + (threadIdx.x >> 6);
    const int lane = threadIdx.x & 63;
    const unsigned long long my = folded[row];
    int cnt = 0;
    for (int j = lane; j <= row; j += 64)
        cnt += (folded[j] == my);
#pragma unroll
    for (int o = 32; o; o >>= 1) cnt += __shfl_xor(cnt, o, 64);
    if (lane == 0) out[row] = rsqrtf((float)cnt);
}

extern "C" void kernel_launch(void* const* d_in, const int* in_sizes, int n_in,
                              void* d_out, int out_size, void* d_ws, size_t ws_size,
                              hipStream_t stream) {
    const float* latent = (const float*)d_in[0];   // [128,64,4096] fp32
    const float* A      = (const float*)d_in[1];   // [128,4096] fp32
    float* out          = (float*)d_out;           // [8192] fp32

    uint32_t* A_sw = (uint32_t*)d_ws;                                        // 1 MB
    unsigned long long* folded = (unsigned long long*)((char*)d_ws + (1 << 20)); // 64 KB

    prep_A<<<256, 256, 0, stream>>>(A, A_sw);
    gemm_pack<<<256, 256, 0, stream>>>(latent, A_sw, folded);
    count_rows<<<2048, 256, 0, stream>>>(folded, out);
}

// Round 2
// 226.266 us; speedup vs baseline: 1.1313x; 1.1313x over previous
//
#include <hip/hip_runtime.h>
#include <stdint.h>

#define D_DIM 4096
#define N_ROWS 8192

typedef __attribute__((ext_vector_type(8))) short bfrag8;
typedef __attribute__((ext_vector_type(4))) float facc4;
typedef unsigned long long u64;

__device__ __forceinline__ uint32_t pack_bf16x2(float lo, float hi) {
    union { float f; uint32_t u; } a, b;
    a.f = lo; b.f = hi;
    return (b.u & 0xFFFF0000u) | (a.u >> 16);   // truncate-to-bf16
}

// ---------------------------------------------------------------------------
// Kernel 0: A fp32 -> bf16, XOR-swizzled per-K-chunk image (see round 1).
// ---------------------------------------------------------------------------
__global__ void __launch_bounds__(256)
prep_A(const float* __restrict__ A, uint32_t* __restrict__ A_sw) {
    const int S = blockIdx.x * 256 + threadIdx.x;  // 0..65535
    const int c = S >> 10;
    const int s = S & 1023;
    const int n = s >> 3;
    const int g = (s & 7) ^ (n & 7);
    const float* src = A + (size_t)n * D_DIM + c * 64 + g * 8;
    float4 f0 = *(const float4*)(src);
    float4 f1 = *(const float4*)(src + 4);
    uint4 o;
    o.x = pack_bf16x2(f0.x, f0.y);
    o.y = pack_bf16x2(f0.z, f0.w);
    o.z = pack_bf16x2(f1.x, f1.y);
    o.w = pack_bf16x2(f1.z, f1.w);
    *(uint4*)(A_sw + (size_t)S * 4) = o;
}

// ---------------------------------------------------------------------------
// Kernel 1a (split-K path): each block = one (split, m-block). 32 rows,
// full N=128, kpb 64-K chunks. fp32 partial C tiles to ws.
// ---------------------------------------------------------------------------
__global__ void __launch_bounds__(256)
gemm_split(const float* __restrict__ L, const uint32_t* __restrict__ A_sw,
           float* __restrict__ partials, int kpb) {
    __shared__ ushort Ls[32 * 72];
    __shared__ uint4 As[1024];

    const int tid  = threadIdx.x;
    const int wave = tid >> 6;
    const int lane = tid & 63;
    const int split = blockIdx.x;
    const int row0 = blockIdx.y * 32;
    const int c  = lane & 15;
    const int q  = lane >> 4;
    const int wm = wave >> 1;
    const int wn = wave & 1;

    const int lrow = tid >> 3;
    const int lf4  = tid & 7;
    const float* lsrc = L + (size_t)(row0 + lrow) * D_DIM + lf4 * 4;
    ushort* ldst = &Ls[lrow * 72 + lf4 * 4];

    facc4 acc[4];
#pragma unroll
    for (int i = 0; i < 4; i++) acc[i] = (facc4){0.f, 0.f, 0.f, 0.f};

    const int kc0 = split * kpb * 64;
    const int kc1 = kc0 + kpb * 64;
    for (int kc = kc0; kc < kc1; kc += 64) {
        const uint32_t* gA = A_sw + (size_t)(kc >> 6) * 4096;
#pragma unroll
        for (int i = 0; i < 4; i++) {
            const int slot0 = wave * 256 + i * 64;
            __builtin_amdgcn_global_load_lds(
                (const __attribute__((address_space(1))) uint32_t*)(gA + (slot0 + lane) * 4),
                (__attribute__((address_space(3))) uint32_t*)(&As[slot0]),
                16, 0, 0);
        }
        float4 f0 = *(const float4*)(lsrc + kc);
        float4 f1 = *(const float4*)(lsrc + kc + 32);
        *(uint2*)ldst        = make_uint2(pack_bf16x2(f0.x, f0.y), pack_bf16x2(f0.z, f0.w));
        *(uint2*)(ldst + 32) = make_uint2(pack_bf16x2(f1.x, f1.y), pack_bf16x2(f1.z, f1.w));
        __syncthreads();

#pragma unroll
        for (int ks = 0; ks < 2; ks++) {
            bfrag8 a = *(const bfrag8*)&Ls[(16 * wm + c) * 72 + ks * 32 + q * 8];
#pragma unroll
            for (int ct = 0; ct < 4; ct++) {
                const int n  = 64 * wn + 16 * ct + c;
                const int gl = ks * 4 + q;
                bfrag8 b = *(const bfrag8*)&As[n * 8 + (gl ^ (n & 7))];
                acc[ct] = __builtin_amdgcn_mfma_f32_16x16x32_bf16(a, b, acc[ct], 0, 0, 0);
            }
        }
        __syncthreads();
    }

    // C/D layout: row = q*4 + reg, col = c (m89/m91-verified, same as round 1)
    float* P = partials + ((size_t)split * N_ROWS * 128);
    const int rb = row0 + 16 * wm + 4 * q;
    const int cb = 64 * wn + c;
#pragma unroll
    for (int ct = 0; ct < 4; ct++)
#pragma unroll
        for (int r = 0; r < 4; r++)
            P[(size_t)(rb + r) * 128 + cb + 16 * ct] = acc[ct][r];
}

// ---------------------------------------------------------------------------
// Kernel 1b: reduce S partials, sign -> 128-bit key -> 64-bit fold.
// One wave per row; lane covers cols (lane, lane+64).
// ---------------------------------------------------------------------------
__global__ void __launch_bounds__(256)
reduce_pack(const float* __restrict__ partials, u64* __restrict__ folded, int S) {
    const int row  = blockIdx.x * 4 + (threadIdx.x >> 6);
    const int lane = threadIdx.x & 63;
    float s0 = 0.f, s1 = 0.f;
    for (int s = 0; s < S; s++) {
        const float* P = partials + ((size_t)s * N_ROWS * 128) + (size_t)row * 128;
        s0 += P[lane];
        s1 += P[lane + 64];
    }
    u64 b0 = __ballot(s0 > 0.0f);
    u64 b1 = __ballot(s1 > 0.0f);
    if (lane == 0) folded[row] = b0 ^ b1;
}

// ---------------------------------------------------------------------------
// Kernel 1-fallback (S=1, tiny ws): round-1 fused gemm+pack (verified).
// ---------------------------------------------------------------------------
__global__ void __launch_bounds__(256)
gemm_pack(const float* __restrict__ L, const uint32_t* __restrict__ A_sw,
          u64* __restrict__ folded) {
    __shared__ ushort Ls[32 * 72];
    __shared__ uint4 As[1024];
    __shared__ u64 halves[2][32];

    const int tid  = threadIdx.x;
    const int wave = tid >> 6;
    const int lane = tid & 63;
    const int row0 = blockIdx.x * 32;
    const int c  = lane & 15;
    const int q  = lane >> 4;
    const int wm = wave >> 1;
    const int wn = wave & 1;

    const int lrow = tid >> 3;
    const int lf4  = tid & 7;
    const float* lsrc = L + (size_t)(row0 + lrow) * D_DIM + lf4 * 4;
    ushort* ldst = &Ls[lrow * 72 + lf4 * 4];

    facc4 acc[4];
#pragma unroll
    for (int i = 0; i < 4; i++) acc[i] = (facc4){0.f, 0.f, 0.f, 0.f};

    for (int kc = 0; kc < D_DIM; kc += 64) {
        const uint32_t* gA = A_sw + (size_t)(kc >> 6) * 4096;
#pragma unroll
        for (int i = 0; i < 4; i++) {
            const int slot0 = wave * 256 + i * 64;
            __builtin_amdgcn_global_load_lds(
                (const __attribute__((address_space(1))) uint32_t*)(gA + (slot0 + lane) * 4),
                (__attribute__((address_space(3))) uint32_t*)(&As[slot0]),
                16, 0, 0);
        }
        float4 f0 = *(const float4*)(lsrc + kc);
        float4 f1 = *(const float4*)(lsrc + kc + 32);
        *(uint2*)ldst        = make_uint2(pack_bf16x2(f0.x, f0.y), pack_bf16x2(f0.z, f0.w));
        *(uint2*)(ldst + 32) = make_uint2(pack_bf16x2(f1.x, f1.y), pack_bf16x2(f1.z, f1.w));
        __syncthreads();

#pragma unroll
        for (int ks = 0; ks < 2; ks++) {
            bfrag8 a = *(const bfrag8*)&Ls[(16 * wm + c) * 72 + ks * 32 + q * 8];
#pragma unroll
            for (int ct = 0; ct < 4; ct++) {
                const int n  = 64 * wn + 16 * ct + c;
                const int gl = ks * 4 + q;
                bfrag8 b = *(const bfrag8*)&As[n * 8 + (gl ^ (n & 7))];
                acc[ct] = __builtin_amdgcn_mfma_f32_16x16x32_bf16(a, b, acc[ct], 0, 0, 0);
            }
        }
        __syncthreads();
    }

    u64 masks[4][4];
#pragma unroll
    for (int ct = 0; ct < 4; ct++)
#pragma unroll
        for (int r = 0; r < 4; r++)
            masks[ct][r] = __ballot(acc[ct][r] > 0.0f);

    if (lane < 16) {
        const int qq = lane >> 2, r = lane & 3;
        u64 half = 0;
#pragma unroll
        for (int ct = 0; ct < 4; ct++) {
            u64 bits = (masks[ct][r] >> (16 * qq)) & 0xFFFFull;
            half |= bits << (16 * ct);
        }
        halves[wn][16 * wm + lane] = half;
    }
    __syncthreads();
    if (tid < 32)
        folded[row0 + tid] = halves[0][tid] ^ halves[1][tid];
}

// ---------------------------------------------------------------------------
// Kernel 2: ordered duplicate count, LDS-staged keys, load-balanced rows.
// 256 blocks x 512 thr; each block copies all keys to LDS once; wave w
// handles rows {g, g+2048, g+4096, g+6144} where g = global wave id.
// ---------------------------------------------------------------------------
__global__ void __launch_bounds__(512)
count_rows(const u64* __restrict__ folded, float* __restrict__ out) {
    __shared__ u64 K[N_ROWS];
    const int tid = threadIdx.x;
    for (int i = tid; i < N_ROWS; i += 512) K[i] = folded[i];
    __syncthreads();

    const int g    = blockIdx.x * 8 + (tid >> 6);   // 0..2047
    const int lane = tid & 63;
    int rows[4];
    u64 my[4];
    int cnt[4] = {0, 0, 0, 0};
#pragma unroll
    for (int r = 0; r < 4; r++) {
        rows[r] = g + 2048 * r;
        my[r] = K[rows[r]];
    }
    const int maxrow = rows[3];
    for (int j = lane; j <= maxrow; j += 64) {
        u64 k = K[j];
#pragma unroll
        for (int r = 0; r < 4; r++)
            cnt[r] += (int)((j <= rows[r]) & (k == my[r]));
    }
#pragma unroll
    for (int r = 0; r < 4; r++) {
        int v = cnt[r];
#pragma unroll
        for (int o = 32; o; o >>= 1) v += __shfl_xor(v, o, 64);
        if (lane == 0) out[rows[r]] = rsqrtf((float)v);
    }
}

extern "C" void kernel_launch(void* const* d_in, const int* in_sizes, int n_in,
                              void* d_out, int out_size, void* d_ws, size_t ws_size,
                              hipStream_t stream) {
    const float* latent = (const float*)d_in[0];   // [128,64,4096] fp32
    const float* A      = (const float*)d_in[1];   // [128,4096] fp32
    float* out          = (float*)d_out;           // [8192] fp32

    uint32_t* A_sw = (uint32_t*)d_ws;                                   // 1 MB
    u64* folded = (u64*)((char*)d_ws + (1 << 20));                      // 64 KB
    float* partials = (float*)((char*)d_ws + (1 << 20) + (1 << 16));    // S * 4 MB

    const size_t base = (1 << 20) + (1 << 16);
    const size_t per_split = (size_t)N_ROWS * 128 * sizeof(float);      // 4 MB
    int S = 0;
    if (ws_size >= base + 8 * per_split)      S = 8;
    else if (ws_size >= base + 4 * per_split) S = 4;
    else if (ws_size >= base + 2 * per_split) S = 2;

    prep_A<<<256, 256, 0, stream>>>(A, A_sw);
    if (S > 0) {
        gemm_split<<<dim3(S, 256), 256, 0, stream>>>(latent, A_sw, partials, 64 / S);
        reduce_pack<<<2048, 256, 0, stream>>>(partials, folded, S);
    } else {
        gemm_pack<<<256, 256, 0, stream>>>(latent, A_sw, folded);
    }
    count_rows<<<256, 512, 0, stream>>>(folded, out);
}